// Round 1
// 153.491 us; speedup vs baseline: 1.1373x; 1.1373x over previous
//
#include <hip/hip_runtime.h>

#define D_MODEL 1024
#define T_SEQ   512
#define B_BATCH 64
#define BGROUP  16   // batches per emb block; grid = (64/16) * 512 = 2048 blocks

typedef float nt_f4 __attribute__((ext_vector_type(4)));

// ---------------------------------------------------------------------------
// Phase 1: per-batch-row scan over T=512, one WAVE (64 lanes) per row.
// Each lane owns 8 consecutive t. Local serial scan + wave shuffle scan.
// No LDS, no barriers. (unchanged — ~5 us, not the bottleneck)
// ---------------------------------------------------------------------------
__global__ __launch_bounds__(64) void gpe_scan_kernel(
    const int* __restrict__ input_ids,
    const int* __restrict__ rel_ids,
    int* __restrict__ cp_role)
{
    const int b    = blockIdx.x;
    const int lane = threadIdx.x;            // 0..63
    const int base = b * T_SEQ + lane * 8;

    const int4 ra = *reinterpret_cast<const int4*>(rel_ids + base);
    const int4 rb = *reinterpret_cast<const int4*>(rel_ids + base + 4);
    const int4 ia = *reinterpret_cast<const int4*>(input_ids + base);
    const int4 ib = *reinterpret_cast<const int4*>(input_ids + base + 4);
    const int rel[8] = {ra.x, ra.y, ra.z, ra.w, rb.x, rb.y, rb.z, rb.w};
    const int id[8]  = {ia.x, ia.y, ia.z, ia.w, ib.x, ib.y, ib.z, ib.w};

    // local exclusive cumsum of inc
    int cl[8];
    int run = 0;
#pragma unroll
    for (int j = 0; j < 8; ++j) { cl[j] = run; run += (rel[j] > 0) ? 1 : 0; }

    // wave inclusive prefix sum of per-lane totals -> exclusive
    int incl = run;
#pragma unroll
    for (int off = 1; off < 64; off <<= 1) {
        const int n = __shfl_up(incl, off);
        if (lane >= off) incl += n;
    }
    const int excl = incl - run;

    int c[8];
#pragma unroll
    for (int j = 0; j < 8; ++j) c[j] = excl + cl[j];

    // prev_rel for j==0 comes from previous lane's rel[7]
    int prev0 = __shfl_up(rel[7], 1);
    if (lane == 0) prev0 = 0;

    // local inclusive cummax of (reset ? c : 0)
    int ml[8];
    int mrun = 0;
#pragma unroll
    for (int j = 0; j < 8; ++j) {
        const int prl  = (j == 0) ? prev0 : rel[j - 1];
        const int mask = (rel[j] == 0 && prl > 0) ? c[j] : 0;
        mrun = max(mrun, mask);
        ml[j] = mrun;
    }

    // wave inclusive prefix max of per-lane maxima -> exclusive
    int minc = mrun;
#pragma unroll
    for (int off = 1; off < 64; off <<= 1) {
        const int n = __shfl_up(minc, off);
        if (lane >= off) minc = max(minc, n);
    }
    int mexcl = __shfl_up(minc, 1);
    if (lane == 0) mexcl = 0;

    int outp[8];
#pragma unroll
    for (int j = 0; j < 8; ++j) {
        const int m    = max(mexcl, ml[j]);
        const int cp   = c[j] - m;
        const int role = (id[j] <= 4) ? 3 : ((rel[j] == 0) ? 2 : 0);
        outp[j] = cp | (role << 16);
    }
    *reinterpret_cast<int4*>(cp_role + base)     = make_int4(outp[0], outp[1], outp[2], outp[3]);
    *reinterpret_cast<int4*>(cp_role + base + 4) = make_int4(outp[4], outp[5], outp[6], outp[7]);
}

// ---------------------------------------------------------------------------
// Phase 2: out[b,t,d] = seq[t,d] + 0.5*chain[cp,d] + 0.3*depth[0,d]
//                       + 0.2*role_table[role,d]          (all f32)
//
// v2 changes vs previous session's best:
//  (1) SCRATCH FIX (rule #20): `float4 basev[4]` indexed by runtime `role`
//      was allocated in scratch (runtime-indexed ext_vector array) ->
//      ~190 MB/iter of hidden scratch traffic in the hot loop. role is only
//      ever {0,2,3}, so keep three NAMED float4 registers and select via
//      ternary (v_cndmask chain, zero memory traffic, localMem must be 0).
//  (2) SAME-t BLOCKING: block = (one t, 16 batches) instead of (one batch,
//      8 consecutive t). seq[t] is now loaded ONCE per block and folded into
//      the precomputed base vectors (base_r = seq + 0.3*depth + 0.2*role_r),
//      eliminating the per-row seq read (-128 MB L2 traffic) and shrinking
//      the per-XCD read working set to the 4 MB chain table (L2-fits).
//      Inner loop: 1 chain load + 2 selects + 4 FMA + 1 NT store per row.
//
// Access shape: 256 threads, thread owns ONE float4 column (d0 = tid*4) ->
// every load/store is a fully-coalesced 1 KB per wave. cp_role reads are
// block-uniform (scalar regs). NT stores: 131 MB output is write-once —
// bypass L2 so the chain table stays L2-resident.
// ---------------------------------------------------------------------------
__global__ __launch_bounds__(256) void gpe_emb_kernel(
    const float* __restrict__ seq_table,    // [512,1024]
    const float* __restrict__ chain_table,  // [1000,1024]
    const float* __restrict__ depth_table,  // [20,1024]
    const float* __restrict__ role_table,   // [4,1024]
    const int* __restrict__ cp_role,        // [B*T] packed cp|role<<16
    float* __restrict__ out)                // [B,T,1024]
{
    const int d0 = threadIdx.x << 2;                 // 0..1020, step 4
    const int t  = blockIdx.x & (T_SEQ - 1);         // one t per block
    const int b0 = (blockIdx.x >> 9) * BGROUP;       // batch group

    // Block-uniform packed cp|role for the 16 rows (scalar loads, issued
    // up-front so latency hides under the base-vector computation).
    int pr[BGROUP];
#pragma unroll
    for (int k = 0; k < BGROUP; ++k)
        pr[k] = cp_role[(b0 + k) * T_SEQ + t];

    // base_r = seq[t] + 0.3*depth[0] + 0.2*role_table[r], r in {0,2,3}.
    // NAMED registers (no array!) so nothing can be demoted to scratch.
    const float4 sv  = *reinterpret_cast<const float4*>(seq_table   + t * D_MODEL + d0);
    const float4 dep = *reinterpret_cast<const float4*>(depth_table + d0);
    const float4 rv0 = *reinterpret_cast<const float4*>(role_table  + 0 * D_MODEL + d0);
    const float4 rv2 = *reinterpret_cast<const float4*>(role_table  + 2 * D_MODEL + d0);
    const float4 rv3 = *reinterpret_cast<const float4*>(role_table  + 3 * D_MODEL + d0);

    float4 sd;   // seq + 0.3*depth
    sd.x = sv.x + 0.3f * dep.x;
    sd.y = sv.y + 0.3f * dep.y;
    sd.z = sv.z + 0.3f * dep.z;
    sd.w = sv.w + 0.3f * dep.w;

    float4 b0v, b2v, b3v;
    b0v.x = sd.x + 0.2f * rv0.x;  b0v.y = sd.y + 0.2f * rv0.y;
    b0v.z = sd.z + 0.2f * rv0.z;  b0v.w = sd.w + 0.2f * rv0.w;
    b2v.x = sd.x + 0.2f * rv2.x;  b2v.y = sd.y + 0.2f * rv2.y;
    b2v.z = sd.z + 0.2f * rv2.z;  b2v.w = sd.w + 0.2f * rv2.w;
    b3v.x = sd.x + 0.2f * rv3.x;  b3v.y = sd.y + 0.2f * rv3.y;
    b3v.z = sd.z + 0.2f * rv3.z;  b3v.w = sd.w + 0.2f * rv3.w;

#pragma unroll
    for (int k = 0; k < BGROUP; ++k) {
        const int cp   = pr[k] & 0xffff;
        const int role = pr[k] >> 16;

        const float4 cv = *reinterpret_cast<const float4*>(chain_table + cp * D_MODEL + d0);

        // role in {0,2,3}; uniform per row -> cndmask/uniform-branch select,
        // never a memory access.
        const float4 bv = (role == 3) ? b3v : ((role == 2) ? b2v : b0v);

        nt_f4 ov;
        ov.x = bv.x + 0.5f * cv.x;
        ov.y = bv.y + 0.5f * cv.y;
        ov.z = bv.z + 0.5f * cv.z;
        ov.w = bv.w + 0.5f * cv.w;

        __builtin_nontemporal_store(
            ov, reinterpret_cast<nt_f4*>(out + ((b0 + k) * T_SEQ + t) * D_MODEL + d0));
    }
}

extern "C" void kernel_launch(void* const* d_in, const int* in_sizes, int n_in,
                              void* d_out, int out_size, void* d_ws, size_t ws_size,
                              hipStream_t stream) {
    const int* input_ids = (const int*)d_in[0];
    const int* rel_ids   = (const int*)d_in[1];
    const float* seq_table   = (const float*)d_in[2];
    const float* chain_table = (const float*)d_in[3];
    const float* depth_table = (const float*)d_in[4];
    const float* role_table  = (const float*)d_in[5];
    float* out = (float*)d_out;

    int* cp_role = (int*)d_ws;  // B*T ints = 128 KB

    gpe_scan_kernel<<<B_BATCH, 64, 0, stream>>>(input_ids, rel_ids, cp_role);

    const int n_blocks = (B_BATCH / BGROUP) * T_SEQ;  // 2048
    gpe_emb_kernel<<<n_blocks, 256, 0, stream>>>(
        seq_table, chain_table, depth_table, role_table, cp_role, out);
}

// Round 2
// 149.550 us; speedup vs baseline: 1.1673x; 1.0263x over previous
//
#include <hip/hip_runtime.h>

#define D_MODEL 1024
#define T_SEQ   512
#define B_BATCH 64
#define BGROUP  16   // batches per emb block; grid = (64/16) * 512 = 2048 blocks

// ---------------------------------------------------------------------------
// Phase 1: per-batch-row scan over T=512, one WAVE (64 lanes) per row.
// Each lane owns 8 consecutive t. Local serial scan + wave shuffle scan.
// No LDS, no barriers. (unchanged — ~5 us, not the bottleneck)
// ---------------------------------------------------------------------------
__global__ __launch_bounds__(64) void gpe_scan_kernel(
    const int* __restrict__ input_ids,
    const int* __restrict__ rel_ids,
    int* __restrict__ cp_role)
{
    const int b    = blockIdx.x;
    const int lane = threadIdx.x;            // 0..63
    const int base = b * T_SEQ + lane * 8;

    const int4 ra = *reinterpret_cast<const int4*>(rel_ids + base);
    const int4 rb = *reinterpret_cast<const int4*>(rel_ids + base + 4);
    const int4 ia = *reinterpret_cast<const int4*>(input_ids + base);
    const int4 ib = *reinterpret_cast<const int4*>(input_ids + base + 4);
    const int rel[8] = {ra.x, ra.y, ra.z, ra.w, rb.x, rb.y, rb.z, rb.w};
    const int id[8]  = {ia.x, ia.y, ia.z, ia.w, ib.x, ib.y, ib.z, ib.w};

    // local exclusive cumsum of inc
    int cl[8];
    int run = 0;
#pragma unroll
    for (int j = 0; j < 8; ++j) { cl[j] = run; run += (rel[j] > 0) ? 1 : 0; }

    // wave inclusive prefix sum of per-lane totals -> exclusive
    int incl = run;
#pragma unroll
    for (int off = 1; off < 64; off <<= 1) {
        const int n = __shfl_up(incl, off);
        if (lane >= off) incl += n;
    }
    const int excl = incl - run;

    int c[8];
#pragma unroll
    for (int j = 0; j < 8; ++j) c[j] = excl + cl[j];

    // prev_rel for j==0 comes from previous lane's rel[7]
    int prev0 = __shfl_up(rel[7], 1);
    if (lane == 0) prev0 = 0;

    // local inclusive cummax of (reset ? c : 0)
    int ml[8];
    int mrun = 0;
#pragma unroll
    for (int j = 0; j < 8; ++j) {
        const int prl  = (j == 0) ? prev0 : rel[j - 1];
        const int mask = (rel[j] == 0 && prl > 0) ? c[j] : 0;
        mrun = max(mrun, mask);
        ml[j] = mrun;
    }

    // wave inclusive prefix max of per-lane maxima -> exclusive
    int minc = mrun;
#pragma unroll
    for (int off = 1; off < 64; off <<= 1) {
        const int n = __shfl_up(minc, off);
        if (lane >= off) minc = max(minc, n);
    }
    int mexcl = __shfl_up(minc, 1);
    if (lane == 0) mexcl = 0;

    int outp[8];
#pragma unroll
    for (int j = 0; j < 8; ++j) {
        const int m    = max(mexcl, ml[j]);
        const int cp   = c[j] - m;
        const int role = (id[j] <= 4) ? 3 : ((rel[j] == 0) ? 2 : 0);
        outp[j] = cp | (role << 16);
    }
    *reinterpret_cast<int4*>(cp_role + base)     = make_int4(outp[0], outp[1], outp[2], outp[3]);
    *reinterpret_cast<int4*>(cp_role + base + 4) = make_int4(outp[4], outp[5], outp[6], outp[7]);
}

// ---------------------------------------------------------------------------
// Phase 2: out[b,t,d] = seq[t,d] + 0.5*chain[cp,d] + 0.3*depth[0,d]
//                       + 0.2*role_table[role,d]          (all f32)
//
// v3 change (SINGLE variable vs v2): nontemporal stores -> PLAIN stores.
// Rationale: emb runs at ~2.4 TB/s effective write BW while the harness
// fill sustains 6.35 TB/s on the same buffer with plain stores. NT stores
// bypass the L2 streaming-write path and were never A/B'd. The L2-residency
// argument NT was protecting is weak: tables total 6 MB and L3 (256 MB)
// backstops any eviction at far-above-HBM bandwidth.
//
// Retained from v2:
//  (1) scratch fix (rule #20): role in {0,2,3} -> three NAMED float4 regs
//      selected by ternary, never a runtime-indexed array.
//  (2) same-t blocking: block = (one t, 16 batches); seq[t] + 0.3*depth
//      folded into precomputed base vectors once per block.
// ---------------------------------------------------------------------------
__global__ __launch_bounds__(256) void gpe_emb_kernel(
    const float* __restrict__ seq_table,    // [512,1024]
    const float* __restrict__ chain_table,  // [1000,1024]
    const float* __restrict__ depth_table,  // [20,1024]
    const float* __restrict__ role_table,   // [4,1024]
    const int* __restrict__ cp_role,        // [B*T] packed cp|role<<16
    float* __restrict__ out)                // [B,T,1024]
{
    const int d0 = threadIdx.x << 2;                 // 0..1020, step 4
    const int t  = blockIdx.x & (T_SEQ - 1);         // one t per block
    const int b0 = (blockIdx.x >> 9) * BGROUP;       // batch group

    // Block-uniform packed cp|role for the 16 rows (scalar loads, issued
    // up-front so latency hides under the base-vector computation).
    int pr[BGROUP];
#pragma unroll
    for (int k = 0; k < BGROUP; ++k)
        pr[k] = cp_role[(b0 + k) * T_SEQ + t];

    // base_r = seq[t] + 0.3*depth[0] + 0.2*role_table[r], r in {0,2,3}.
    // NAMED registers (no array!) so nothing can be demoted to scratch.
    const float4 sv  = *reinterpret_cast<const float4*>(seq_table   + t * D_MODEL + d0);
    const float4 dep = *reinterpret_cast<const float4*>(depth_table + d0);
    const float4 rv0 = *reinterpret_cast<const float4*>(role_table  + 0 * D_MODEL + d0);
    const float4 rv2 = *reinterpret_cast<const float4*>(role_table  + 2 * D_MODEL + d0);
    const float4 rv3 = *reinterpret_cast<const float4*>(role_table  + 3 * D_MODEL + d0);

    float4 sd;   // seq + 0.3*depth
    sd.x = sv.x + 0.3f * dep.x;
    sd.y = sv.y + 0.3f * dep.y;
    sd.z = sv.z + 0.3f * dep.z;
    sd.w = sv.w + 0.3f * dep.w;

    float4 b0v, b2v, b3v;
    b0v.x = sd.x + 0.2f * rv0.x;  b0v.y = sd.y + 0.2f * rv0.y;
    b0v.z = sd.z + 0.2f * rv0.z;  b0v.w = sd.w + 0.2f * rv0.w;
    b2v.x = sd.x + 0.2f * rv2.x;  b2v.y = sd.y + 0.2f * rv2.y;
    b2v.z = sd.z + 0.2f * rv2.z;  b2v.w = sd.w + 0.2f * rv2.w;
    b3v.x = sd.x + 0.2f * rv3.x;  b3v.y = sd.y + 0.2f * rv3.y;
    b3v.z = sd.z + 0.2f * rv3.z;  b3v.w = sd.w + 0.2f * rv3.w;

#pragma unroll
    for (int k = 0; k < BGROUP; ++k) {
        const int cp   = pr[k] & 0xffff;
        const int role = pr[k] >> 16;

        const float4 cv = *reinterpret_cast<const float4*>(chain_table + cp * D_MODEL + d0);

        // role in {0,2,3}; uniform per row -> cndmask/uniform-branch select,
        // never a memory access.
        const float4 bv = (role == 3) ? b3v : ((role == 2) ? b2v : b0v);

        float4 ov;
        ov.x = bv.x + 0.5f * cv.x;
        ov.y = bv.y + 0.5f * cv.y;
        ov.z = bv.z + 0.5f * cv.z;
        ov.w = bv.w + 0.5f * cv.w;

        *reinterpret_cast<float4*>(out + ((b0 + k) * T_SEQ + t) * D_MODEL + d0) = ov;
    }
}

extern "C" void kernel_launch(void* const* d_in, const int* in_sizes, int n_in,
                              void* d_out, int out_size, void* d_ws, size_t ws_size,
                              hipStream_t stream) {
    const int* input_ids = (const int*)d_in[0];
    const int* rel_ids   = (const int*)d_in[1];
    const float* seq_table   = (const float*)d_in[2];
    const float* chain_table = (const float*)d_in[3];
    const float* depth_table = (const float*)d_in[4];
    const float* role_table  = (const float*)d_in[5];
    float* out = (float*)d_out;

    int* cp_role = (int*)d_ws;  // B*T ints = 128 KB

    gpe_scan_kernel<<<B_BATCH, 64, 0, stream>>>(input_ids, rel_ids, cp_role);

    const int n_blocks = (B_BATCH / BGROUP) * T_SEQ;  // 2048
    gpe_emb_kernel<<<n_blocks, 256, 0, stream>>>(
        seq_table, chain_table, depth_table, role_table, cp_role, out);
}